// Round 3
// baseline (516.747 us; speedup 1.0000x reference)
//
#include <hip/hip_runtime.h>

// DualSPRTLinear: out = x @ W^T, W = dequant(ternary, group scales).
// bf16 MFMA GEMM M=8192, N=4096, K=4096, B stored [N][K] (B^T form).
// Round 3: 256x256 8-phase template, MFMA shape 32x32x16 (higher pipe ceiling,
// half the instruction count), rebalanced ds_reads 12/8/4/0 across phases.

typedef __attribute__((ext_vector_type(8))) short      bf16x8;
typedef __attribute__((ext_vector_type(16))) float     f32x16;
typedef __attribute__((ext_vector_type(8))) float      f32x8;
typedef __attribute__((ext_vector_type(8))) unsigned short u16x8;
typedef __attribute__((ext_vector_type(4))) int        i32x4;

#define M_DIM 8192
#define N_DIM 4096
#define K_DIM 4096
#define BM 256
#define BN 256
#define BK 64
#define NT (K_DIM / BK)   // 64 K-tiles
#define THREADS 512

__device__ __forceinline__ unsigned short f2bf(float f) {
  union { float f; unsigned u; } v; v.f = f;
  unsigned u = v.u;
  u += 0x7FFFu + ((u >> 16) & 1u);
  return (unsigned short)(u >> 16);
}

__global__ void cvt_x_kernel(const float* __restrict__ x,
                             unsigned short* __restrict__ y, int n8) {
  int stride = gridDim.x * blockDim.x;
  for (int i = blockIdx.x * blockDim.x + threadIdx.x; i < n8; i += stride) {
    f32x8 f = ((const f32x8*)x)[i];
    u16x8 o;
#pragma unroll
    for (int j = 0; j < 8; ++j) o[j] = f2bf(f[j]);
    ((u16x8*)y)[i] = o;
  }
}

__global__ void cvt_w_kernel(const int* __restrict__ t, const float* __restrict__ s,
                             unsigned short* __restrict__ w, int n8) {
  int stride = gridDim.x * blockDim.x;
  for (int i = blockIdx.x * blockDim.x + threadIdx.x; i < n8; i += stride) {
    i32x4 a = ((const i32x4*)t)[2 * i + 0];
    i32x4 b = ((const i32x4*)t)[2 * i + 1];
    float sc = s[i >> 4];
    u16x8 o;
    o[0] = f2bf((float)a[0] * sc); o[1] = f2bf((float)a[1] * sc);
    o[2] = f2bf((float)a[2] * sc); o[3] = f2bf((float)a[3] * sc);
    o[4] = f2bf((float)b[0] * sc); o[5] = f2bf((float)b[1] * sc);
    o[6] = f2bf((float)b[2] * sc); o[7] = f2bf((float)b[3] * sc);
    ((u16x8*)w)[i] = o;
  }
}

// ---------------------------------------------------------------------------
// 256x256x64 8-wave 8-phase GEMM, mfma_f32_32x32x16_bf16.
// Wave tile 128x64 = 4(mf) x 2(nf) frags of 32x32; K-tile = 4 ks-steps of 16.
// LDS (dynamic, 128 KiB): buf c at c*65536: A tile [256][64] (32KB), then B.
// T2 swizzle: element (row,col) at byte row*128 + 2*(col ^ ((row&7)<<3)).
// Staged via linear global_load_lds dest + inverse-swizzled global source.
// ---------------------------------------------------------------------------
__global__ __launch_bounds__(THREADS, 2)
void gemm256_kernel(const unsigned short* __restrict__ A,
                    const unsigned short* __restrict__ B,
                    float* __restrict__ C) {
  extern __shared__ char smem[];

  const int tid  = threadIdx.x;
  const int lane = tid & 63;
  const int wave = tid >> 6;     // 0..7
  const int wm   = wave >> 2;    // 0..1  (M half)
  const int wn   = wave & 3;     // 0..3  (N quarter)

  // T1: XCD-bijective swizzle; grid = 512, 512 % 8 == 0.
  const int blk = blockIdx.x;
  const int wg  = (blk & 7) * (512 / 8) + (blk >> 3);
  const int bm  = wg >> 4;       // 32 M-blocks
  const int bn  = wg & 15;       // 16 N-blocks

  // Staging source (per-thread, inverse-swizzled): thread covers LDS bytes
  // [j*8192 + wave*1024 + lane*16) -> row = j*64 + tid/8, colbyte = (tid&7)*16.
  const int srow = tid >> 3;                         // 0..63
  const int scol = 8 * ((tid & 7) ^ (srow & 7));     // swizzled col (elements)
  const unsigned short* Ap = A + (size_t)(bm * BM + srow) * K_DIM + scol;
  const unsigned short* Bp = B + (size_t)(bn * BN + srow) * K_DIM + scol;
  const int ldsWave = wave * 1024;

  // ab: 0 = A tile, 1 = B tile. j in 0..3 covers rows [64j, 64j+64).
  auto STAGE = [&](int c, int ab, int T, int j) {
    const unsigned short* src =
        (ab == 0 ? Ap : Bp) + (size_t)j * 64 * K_DIM + (size_t)T * BK;
    char* dst = smem + c * 65536 + ab * 32768 + j * 8192 + ldsWave;
    __builtin_amdgcn_global_load_lds(
        (const __attribute__((address_space(1))) void*)src,
        (__attribute__((address_space(3))) void*)dst, 16, 0, 0);
  };

  // Fragment reads (swizzled). 32x32x16 operand layout:
  // row = lane&31, k = (lane>>5)*8 + e  (standard extension of verified 16x16).
  const int r32 = lane & 31;
  const int kh  = lane >> 5;           // 0..1
  const int swz = (lane & 7) << 3;     // element-space XOR ((row&7)<<3)
  auto RD_A = [&](int c, int mf, int ks) -> bf16x8 {
    const int row = wm * 128 + mf * 32 + r32;
    const int col = (ks * 16 + kh * 8) ^ swz;
    return *(const bf16x8*)(smem + c * 65536 + (row * 64 + col) * 2);
  };
  auto RD_B = [&](int c, int nf, int ks) -> bf16x8 {
    const int row = wn * 64 + nf * 32 + r32;
    const int col = (ks * 16 + kh * 8) ^ swz;
    return *(const bf16x8*)(smem + c * 65536 + 32768 + (row * 64 + col) * 2);
  };

  f32x16 acc[4][2];
#pragma unroll
  for (int mf = 0; mf < 4; ++mf)
#pragma unroll
    for (int nf = 0; nf < 2; ++nf)
#pragma unroll
      for (int j = 0; j < 16; ++j) acc[mf][nf][j] = 0.f;

  // ---- prologue: tile0 (A+B) -> buf0; tile1 B -> buf1 ----
#pragma unroll
  for (int j = 0; j < 4; ++j) STAGE(0, 0, 0, j);
#pragma unroll
  for (int j = 0; j < 4; ++j) STAGE(0, 1, 0, j);
#pragma unroll
  for (int j = 0; j < 4; ++j) STAGE(1, 1, 1, j);
  asm volatile("s_waitcnt vmcnt(4)" ::: "memory");  // tile0 fully landed
  __builtin_amdgcn_s_barrier();

  for (int t = 0; t < NT; ++t) {
    const int cur = t & 1;
    const int nxt = cur ^ 1;
    bf16x8 aLo[2][4], aHi[2][4], bF[2][4];

    // ===== P1: Q(mf01 x nf0). reads: A-lo (8) + B0 (4) = 12 =====
#pragma unroll
    for (int mf = 0; mf < 2; ++mf)
#pragma unroll
      for (int ks = 0; ks < 4; ++ks) aLo[mf][ks] = RD_A(cur, mf, ks);
#pragma unroll
    for (int ks = 0; ks < 4; ++ks) bF[0][ks] = RD_B(cur, 0, ks);
    if (t + 1 < NT) { STAGE(nxt, 0, t + 1, 0); STAGE(nxt, 0, t + 1, 1); }
    __builtin_amdgcn_s_barrier();
    asm volatile("s_waitcnt lgkmcnt(0)" ::: "memory");
    __builtin_amdgcn_sched_barrier(0);
    __builtin_amdgcn_s_setprio(1);
#pragma unroll
    for (int mf = 0; mf < 2; ++mf)
#pragma unroll
      for (int ks = 0; ks < 4; ++ks)
        acc[mf][0] = __builtin_amdgcn_mfma_f32_32x32x16_bf16(
            aLo[mf][ks], bF[0][ks], acc[mf][0], 0, 0, 0);
    __builtin_amdgcn_s_setprio(0);
    __builtin_amdgcn_s_barrier();

    // ===== P2: Q(mf01 x nf1). reads: B1 (4) + A-hi ks01 (4) = 8 =====
#pragma unroll
    for (int ks = 0; ks < 4; ++ks) bF[1][ks] = RD_B(cur, 1, ks);
#pragma unroll
    for (int mf = 0; mf < 2; ++mf)
#pragma unroll
      for (int ks = 0; ks < 2; ++ks) aHi[mf][ks] = RD_A(cur, mf + 2, ks);
    if (t + 1 < NT) { STAGE(nxt, 0, t + 1, 2); STAGE(nxt, 0, t + 1, 3); }
    __builtin_amdgcn_s_barrier();
    asm volatile("s_waitcnt lgkmcnt(0)" ::: "memory");
    __builtin_amdgcn_sched_barrier(0);
    __builtin_amdgcn_s_setprio(1);
#pragma unroll
    for (int mf = 0; mf < 2; ++mf)
#pragma unroll
      for (int ks = 0; ks < 4; ++ks)
        acc[mf][1] = __builtin_amdgcn_mfma_f32_32x32x16_bf16(
            aLo[mf][ks], bF[1][ks], acc[mf][1], 0, 0, 0);
    __builtin_amdgcn_s_setprio(0);
    __builtin_amdgcn_s_barrier();

    // ===== P3: Q(mf23 x nf0). reads: A-hi ks23 (4) =====
    // B region of buf[cur] fully read (P2-end barrier) -> stage t+2 B there.
#pragma unroll
    for (int mf = 0; mf < 2; ++mf)
#pragma unroll
      for (int ks = 2; ks < 4; ++ks) aHi[mf][ks] = RD_A(cur, mf + 2, ks);
    if (t + 2 < NT) { STAGE(cur, 1, t + 2, 0); STAGE(cur, 1, t + 2, 1); }
    __builtin_amdgcn_s_barrier();
    asm volatile("s_waitcnt lgkmcnt(0)" ::: "memory");
    __builtin_amdgcn_sched_barrier(0);
    __builtin_amdgcn_s_setprio(1);
#pragma unroll
    for (int mf = 0; mf < 2; ++mf)
#pragma unroll
      for (int ks = 0; ks < 4; ++ks)
        acc[mf + 2][0] = __builtin_amdgcn_mfma_f32_32x32x16_bf16(
            aHi[mf][ks], bF[0][ks], acc[mf + 2][0], 0, 0, 0);
    __builtin_amdgcn_s_setprio(0);
    __builtin_amdgcn_s_barrier();

    // ===== P4: Q(mf23 x nf1). no reads =====
    if (t + 2 < NT) { STAGE(cur, 1, t + 2, 2); STAGE(cur, 1, t + 2, 3); }
    __builtin_amdgcn_s_barrier();
    __builtin_amdgcn_s_setprio(1);
#pragma unroll
    for (int mf = 0; mf < 2; ++mf)
#pragma unroll
      for (int ks = 0; ks < 4; ++ks)
        acc[mf + 2][1] = __builtin_amdgcn_mfma_f32_32x32x16_bf16(
            aHi[mf][ks], bF[1][ks], acc[mf + 2][1], 0, 0, 0);
    __builtin_amdgcn_s_setprio(0);
    // iteration end: tile t+1 must be fully landed before next P1 reads it.
    if (t + 2 < NT) {
      asm volatile("s_waitcnt vmcnt(4)" ::: "memory");  // leave t+2's 4 B-loads
    } else if (t + 1 < NT) {
      asm volatile("s_waitcnt vmcnt(0)" ::: "memory");
    }
    __builtin_amdgcn_s_barrier();
  }

  // ---- epilogue: 32x32 C/D map: col = lane&31,
  //      row = (reg&3) + 8*(reg>>2) + 4*(lane>>5)  (m74/m101 verified) ----
  const int cl = lane & 31;
  const int rh = (lane >> 5) * 4;
  const size_t row0 = (size_t)bm * BM + wm * 128;
  const size_t col0 = (size_t)bn * BN + wn * 64;
#pragma unroll
  for (int mf = 0; mf < 4; ++mf)
#pragma unroll
    for (int nf = 0; nf < 2; ++nf)
#pragma unroll
      for (int reg = 0; reg < 16; ++reg) {
        const int rt = (reg & 3) + 8 * (reg >> 2) + rh;
        C[(row0 + mf * 32 + rt) * N_DIM + col0 + nf * 32 + cl] =
            acc[mf][nf][reg];
      }
}

extern "C" void kernel_launch(void* const* d_in, const int* in_sizes, int n_in,
                              void* d_out, int out_size, void* d_ws, size_t ws_size,
                              hipStream_t stream) {
  const float* x      = (const float*)d_in[0];
  const int*   tern   = (const int*)d_in[1];
  const float* scales = (const float*)d_in[2];
  float* out = (float*)d_out;

  unsigned short* xb = (unsigned short*)d_ws;
  unsigned short* wb = (unsigned short*)d_ws + (size_t)M_DIM * K_DIM;

  cvt_x_kernel<<<2048, 256, 0, stream>>>(x, xb, M_DIM * K_DIM / 8);
  cvt_w_kernel<<<2048, 256, 0, stream>>>(tern, scales, wb, N_DIM * K_DIM / 8);

  // 128 KiB dynamic LDS needs the opt-in attribute (host-side, capture-safe).
  hipFuncSetAttribute((const void*)gemm256_kernel,
                      hipFuncAttributeMaxDynamicSharedMemorySize, 131072);
  const int grid = (M_DIM / BM) * (N_DIM / BN);  // 32 * 16 = 512
  gemm256_kernel<<<grid, THREADS, 131072, stream>>>(xb, wb, out);
}